// Round 12
// baseline (318.076 us; speedup 1.0000x reference)
//
#include <hip/hip_runtime.h>
#include <hip/hip_bf16.h>

#define N_NODES 50000
#define N_EDGES 800000
#define BSHIFT  5
#define BUCKS   1563           // ceil(50000 / 32)
#define NPAD    50016          // BUCKS * 32
#define BSTRIDE 1024           // slots per bucket (mean 512, ~22 sigma headroom)
#define BCAP    1024
#define IN_DIM  100
#define HID     128
#define BN_EPS  1e-5f
#define NSLICE  32             // stats atomic slices (depth 1563/32 ~ 49 per address)

typedef unsigned int uint;
typedef unsigned short u16;
typedef __attribute__((ext_vector_type(8))) unsigned short us8;
typedef __attribute__((ext_vector_type(8))) short s8;       // bf16 MFMA frag
typedef __attribute__((ext_vector_type(16))) float f16v;    // 32x32 accumulator

__device__ __forceinline__ u16 f2bf(float f) {
    uint u = __builtin_bit_cast(uint, f);
    uint r = (u + 0x7FFFu + ((u >> 16) & 1u)) >> 16;   // RNE
    return (u16)r;
}
__device__ __forceinline__ uint pack2(float a, float b) {
    return (uint)f2bf(a) | ((uint)f2bf(b) << 16);
}
__device__ __forceinline__ float bflo(uint p) { return __builtin_bit_cast(float, p << 16); }
__device__ __forceinline__ float bfhi(uint p) { return __builtin_bit_cast(float, p & 0xFFFF0000u); }

// ---------------------------------------------------------------------------
// Bucketed edge scatter (unchanged)
// ---------------------------------------------------------------------------
__global__ __launch_bounds__(1024) void bucket_scatter_blk(
    const int* __restrict__ src, const int* __restrict__ dst,
    int* __restrict__ bcursor, uint* __restrict__ ebuf) {
    __shared__ int h[BUCKS];
    __shared__ int gb[BUCKS];
    int t = threadIdx.x;
    for (int i = t; i < BUCKS; i += 1024) h[i] = 0;
    __syncthreads();
    int base = blockIdx.x * 8192;
    int myb[8]; uint myv[8];
    #pragma unroll
    for (int r = 0; r < 8; ++r) {
        int e = base + r * 1024 + t;
        int b = -1; uint val = 0;
        if (e < N_EDGES) {
            int d = dst[e];
            b = d >> BSHIFT;
            val = (uint)src[e] | ((uint)(d & 31) << 16);
            atomicAdd(&h[b], 1);
        }
        myb[r] = b; myv[r] = val;
    }
    __syncthreads();
    for (int i = t; i < BUCKS; i += 1024) {
        int c = h[i];
        gb[i] = c ? (i * BSTRIDE + atomicAdd(&bcursor[i], c)) : 0;
        h[i] = 0;
    }
    __syncthreads();
    #pragma unroll
    for (int r = 0; r < 8; ++r) {
        int b = myb[r];
        if (b >= 0) {
            int pos = gb[b] + atomicAdd(&h[b], 1);
            ebuf[pos] = myv[r];
        }
    }
}

// ---------------------------------------------------------------------------
// Per-bucket CSR build, once: sorted src list (u16) + row offsets to global.
// One wave per bucket.
// ---------------------------------------------------------------------------
__global__ __launch_bounds__(64) void bucket_sort(
    const uint* __restrict__ ebuf, const int* __restrict__ bcursor,
    u16* __restrict__ sbuf, int* __restrict__ rob) {
    __shared__ uint eL[BCAP];
    __shared__ int cnt[32], ro[33], cur[32];
    int b = blockIdx.x, t = threadIdx.x;
    int n = bcursor[b];
    if (n > BCAP) n = BCAP;
    if (t < 32) cnt[t] = 0;
    __syncthreads();
    for (int i = t; i < n; i += 64) {
        uint p = ebuf[b * BSTRIDE + i];
        eL[i] = p;
        atomicAdd(&cnt[p >> 16], 1);
    }
    __syncthreads();
    if (t < 32) {
        int v = cnt[t];
        int s = v;
        #pragma unroll
        for (int off = 1; off < 32; off <<= 1) {
            int u = __shfl_up(s, off, 64);
            if (t >= off) s += u;
        }
        ro[t] = s - v;
        cur[t] = s - v;
        if (t == 31) ro[32] = s;
    }
    __syncthreads();
    for (int i = t; i < n; i += 64) {
        uint p = eL[i];
        int pos = atomicAdd(&cur[p >> 16], 1);
        sbuf[b * BSTRIDE + pos] = (u16)(p & 0xFFFFu);
    }
    if (t < 33) rob[b * 34 + t] = ro[t];
}

// ---------------------------------------------------------------------------
// One cast kernel: x -> bf16 padded [NPAD][128] + 4 weights transposed
// ---------------------------------------------------------------------------
__global__ void cast_all(const float* __restrict__ x,
                         const float* __restrict__ W_l0, const float* __restrict__ W_r0,
                         const float* __restrict__ W_l1, const float* __restrict__ W_r1,
                         u16* __restrict__ xb, u16* __restrict__ Wt) {
    int idx = blockIdx.x * 256 + threadIdx.x;
    if (idx < NPAD * 128) {
        int row = idx >> 7, k = idx & 127;
        float v = (row < N_NODES && k < IN_DIM) ? x[row * IN_DIM + k] : 0.f;
        xb[idx] = f2bf(v);
        return;
    }
    int i2 = idx - NPAD * 128;
    if (i2 >= 4 * 16384) return;
    int w = i2 >> 14, i3 = i2 & 16383;
    const float* s = (w == 0) ? W_l0 : (w == 1) ? W_r0 : (w == 2) ? W_l1 : W_r1;
    int Ks = (w < 2) ? IN_DIM : HID;
    int n = i3 >> 7, k = i3 & 127;
    float v = (k < Ks) ? s[k * 128 + n] : 0.f;
    Wt[i2] = f2bf(v);
}

// ---------------------------------------------------------------------------
// Feature-sliced gather-mean: one wave per (bucket, 16-col slice).
// slice = blockIdx % 8 -> on round-robin XCD dispatch each XCD sees one
// slice (3.2 MB of 64B lines, fits 4 MB L2). Lane-pair owns a node; 4-deep
// unrolled edge loop. Writes aggb column stripe.
// ---------------------------------------------------------------------------
__global__ __launch_bounds__(64) void agg_sliced(
    const u16* __restrict__ sbuf, const int* __restrict__ rob,
    const u16* __restrict__ X, u16* __restrict__ aggb) {
    int bid = blockIdx.x;
    int slice = bid & 7;
    int b = bid >> 3;
    int t = threadIdx.x;
    int node = t >> 1, half = t & 1;
    int rb = rob[b * 34 + node], re = rob[b * 34 + node + 1];
    const u16* base = X + slice * 16 + half * 8;
    const u16* sb = sbuf + b * BSTRIDE;

    float a0 = 0.f, a1 = 0.f, a2 = 0.f, a3 = 0.f;
    float a4 = 0.f, a5 = 0.f, a6 = 0.f, a7 = 0.f;
    int e = rb;
    for (; e + 4 <= re; e += 4) {
        int s0 = sb[e], s1 = sb[e + 1], s2 = sb[e + 2], s3 = sb[e + 3];
        uint4 v0 = *(const uint4*)(base + (size_t)s0 * 128);
        uint4 v1 = *(const uint4*)(base + (size_t)s1 * 128);
        uint4 v2 = *(const uint4*)(base + (size_t)s2 * 128);
        uint4 v3 = *(const uint4*)(base + (size_t)s3 * 128);
        a0 += (bflo(v0.x) + bflo(v1.x)) + (bflo(v2.x) + bflo(v3.x));
        a1 += (bfhi(v0.x) + bfhi(v1.x)) + (bfhi(v2.x) + bfhi(v3.x));
        a2 += (bflo(v0.y) + bflo(v1.y)) + (bflo(v2.y) + bflo(v3.y));
        a3 += (bfhi(v0.y) + bfhi(v1.y)) + (bfhi(v2.y) + bfhi(v3.y));
        a4 += (bflo(v0.z) + bflo(v1.z)) + (bflo(v2.z) + bflo(v3.z));
        a5 += (bfhi(v0.z) + bfhi(v1.z)) + (bfhi(v2.z) + bfhi(v3.z));
        a6 += (bflo(v0.w) + bflo(v1.w)) + (bflo(v2.w) + bflo(v3.w));
        a7 += (bfhi(v0.w) + bfhi(v1.w)) + (bfhi(v2.w) + bfhi(v3.w));
    }
    for (; e < re; ++e) {
        uint4 v0 = *(const uint4*)(base + (size_t)sb[e] * 128);
        a0 += bflo(v0.x); a1 += bfhi(v0.x);
        a2 += bflo(v0.y); a3 += bfhi(v0.y);
        a4 += bflo(v0.z); a5 += bfhi(v0.z);
        a6 += bflo(v0.w); a7 += bfhi(v0.w);
    }
    int gnode = b * 32 + node;
    if (gnode < N_NODES) {
        float inv = 1.0f / fmaxf((float)(re - rb), 1.0f);
        uint4 o;
        o.x = pack2(a0 * inv, a1 * inv);
        o.y = pack2(a2 * inv, a3 * inv);
        o.z = pack2(a4 * inv, a5 * inv);
        o.w = pack2(a6 * inv, a7 * inv);
        *(uint4*)(aggb + (size_t)gnode * 128 + slice * 16 + half * 8) = o;
    }
}

// ---------------------------------------------------------------------------
// Dual GEMM + bias + BN stats: 32-row tiles, A tiles LDS-staged (1x traffic),
// B direct from global (L2-hot Wt). One 32x32 MFMA col-tile per wave.
// ---------------------------------------------------------------------------
template <int WRITE_BF16>
__global__ __launch_bounds__(256) void gemm_all(
    const u16* __restrict__ Agg, const u16* __restrict__ X,
    const u16* __restrict__ WtL, const u16* __restrict__ WtR,
    const float* __restrict__ bias,
    float* __restrict__ outf, u16* __restrict__ outb,
    float* __restrict__ gstats) {
    __shared__ u16 Aa[32][136];
    __shared__ u16 Ax[32][136];
    __shared__ float s1L[128], s2L[128];

    int b = blockIdx.x, t = threadIdx.x;
    int row0 = b * 32;
    int wave = t >> 6, lane = t & 63;
    if (t < 128) { s1L[t] = 0.f; s2L[t] = 0.f; }

    // stage both A tiles: 32 rows x 128 u16 each (512 uint4 per tile)
    #pragma unroll
    for (int p = 0; p < 2; ++p) {
        int idx = p * 256 + t;
        int r = idx >> 4, c = idx & 15;
        *(us8*)&Aa[r][c * 8] = *(const us8*)(Agg + (size_t)(row0 + r) * 128 + c * 8);
        *(us8*)&Ax[r][c * 8] = *(const us8*)(X + (size_t)(row0 + r) * 128 + c * 8);
    }
    __syncthreads();

    int m31 = lane & 31;
    int kh  = lane >> 5;
    int cn = wave * 32;
    f16v acc = (f16v)0.f;

    {
        s8 a_nxt = *(const s8*)&Aa[m31][kh * 8];
        s8 b_nxt = *(const s8*)(WtL + (cn + m31) * 128 + kh * 8);
        #pragma unroll
        for (int ks = 0; ks < 8; ++ks) {
            s8 a_cur = a_nxt, b_cur = b_nxt;
            if (ks < 7) {
                a_nxt = *(const s8*)&Aa[m31][(ks + 1) * 16 + kh * 8];
                b_nxt = *(const s8*)(WtL + (cn + m31) * 128 + (ks + 1) * 16 + kh * 8);
            }
            acc = __builtin_amdgcn_mfma_f32_32x32x16_bf16(a_cur, b_cur, acc, 0, 0, 0);
        }
    }
    {
        s8 a_nxt = *(const s8*)&Ax[m31][kh * 8];
        s8 b_nxt = *(const s8*)(WtR + (cn + m31) * 128 + kh * 8);
        #pragma unroll
        for (int ks = 0; ks < 8; ++ks) {
            s8 a_cur = a_nxt, b_cur = b_nxt;
            if (ks < 7) {
                a_nxt = *(const s8*)&Ax[m31][(ks + 1) * 16 + kh * 8];
                b_nxt = *(const s8*)(WtR + (cn + m31) * 128 + (ks + 1) * 16 + kh * 8);
            }
            acc = __builtin_amdgcn_mfma_f32_32x32x16_bf16(a_cur, b_cur, acc, 0, 0, 0);
        }
    }

    // epilogue: store + BN partial stats
    // C/D 32x32: col=lane&31, row=(reg&3)+8*(reg>>2)+4*(lane>>5)  [m74/m101]
    {
        int col = cn + m31;
        float bv = bias[col];
        float s1 = 0.f, s2 = 0.f;
        #pragma unroll
        for (int reg = 0; reg < 16; ++reg) {
            int rowin = (reg & 3) + 8 * (reg >> 2) + 4 * kh;
            int row = row0 + rowin;
            if (row < N_NODES) {
                float v = acc[reg] + bv;
                if (WRITE_BF16)
                    outb[(size_t)row * 128 + col] = f2bf(v);
                else
                    outf[(size_t)row * 128 + col] = v;
                s1 += v;
                s2 = fmaf(v, v, s2);
            }
        }
        s1 += __shfl_xor(s1, 32, 64);
        s2 += __shfl_xor(s2, 32, 64);
        if (lane < 32) {
            atomicAdd(&s1L[col], s1);
            atomicAdd(&s2L[col], s2);
        }
    }
    __syncthreads();
    int slice = b & (NSLICE - 1);
    if (t < 128) {
        atomicAdd(&gstats[slice * 256 + t], s1L[t]);
        atomicAdd(&gstats[slice * 256 + 128 + t], s2L[t]);
    }
}

// ---------------------------------------------------------------------------
// BN(+ReLU) in-place on raw bf16 h (layer-0 -> layer-1 handoff).
// ---------------------------------------------------------------------------
__global__ void bn_relu_inplace(u16* __restrict__ hb,
                                const float* __restrict__ gstats,
                                const float* __restrict__ gamma,
                                const float* __restrict__ beta,
                                float inv_n, int totalv) {
    __shared__ float ss[256];
    int t = threadIdx.x;
    if (t < 128) {
        float m = 0.f, q = 0.f;
        #pragma unroll
        for (int s = 0; s < NSLICE; ++s) {
            m += gstats[s * 256 + t];
            q += gstats[s * 256 + 128 + t];
        }
        float mean = m * inv_n;
        float var = q * inv_n - mean * mean;
        float inv = 1.0f / sqrtf(var + BN_EPS);
        float sc = gamma[t] * inv;
        ss[t] = sc;
        ss[128 + t] = beta[t] - mean * sc;
    }
    __syncthreads();
    for (int i = blockIdx.x * 256 + t; i < totalv; i += gridDim.x * 256) {
        int cg = (i & 15) * 8;
        uint4 p = ((const uint4*)hb)[i];
        float4 scA = *(const float4*)&ss[cg];
        float4 scB = *(const float4*)&ss[cg + 4];
        float4 shA = *(const float4*)&ss[128 + cg];
        float4 shB = *(const float4*)&ss[128 + cg + 4];
        float r0 = fmaxf(fmaf(bflo(p.x), scA.x, shA.x), 0.f);
        float r1 = fmaxf(fmaf(bfhi(p.x), scA.y, shA.y), 0.f);
        float r2 = fmaxf(fmaf(bflo(p.y), scA.z, shA.z), 0.f);
        float r3 = fmaxf(fmaf(bfhi(p.y), scA.w, shA.w), 0.f);
        float r4 = fmaxf(fmaf(bflo(p.z), scB.x, shB.x), 0.f);
        float r5 = fmaxf(fmaf(bfhi(p.z), scB.y, shB.y), 0.f);
        float r6 = fmaxf(fmaf(bflo(p.w), scB.z, shB.z), 0.f);
        float r7 = fmaxf(fmaf(bfhi(p.w), scB.w, shB.w), 0.f);
        uint4 o;
        o.x = pack2(r0, r1);
        o.y = pack2(r2, r3);
        o.z = pack2(r4, r5);
        o.w = pack2(r6, r7);
        ((uint4*)hb)[i] = o;
    }
}

// final BN, fp32 in-place on d_out
__global__ void bn_apply_kernel(float* __restrict__ h,
                                const float* __restrict__ gstats,
                                const float* __restrict__ gamma,
                                const float* __restrict__ beta,
                                float inv_n, int total4) {
    __shared__ float ss[256];
    int t = threadIdx.x;
    if (t < 128) {
        float m = 0.f, q = 0.f;
        #pragma unroll
        for (int s = 0; s < NSLICE; ++s) {
            m += gstats[s * 256 + t];
            q += gstats[s * 256 + 128 + t];
        }
        float mean = m * inv_n;
        float var = q * inv_n - mean * mean;
        float inv = 1.0f / sqrtf(var + BN_EPS);
        float sc = gamma[t] * inv;
        ss[t] = sc;
        ss[128 + t] = beta[t] - mean * sc;
    }
    __syncthreads();
    for (int i = blockIdx.x * 256 + t; i < total4; i += gridDim.x * 256) {
        int cg = i & 31;
        float4 v = ((float4*)h)[i];
        float4 sc = *(const float4*)&ss[cg * 4];
        float4 sh = *(const float4*)&ss[128 + cg * 4];
        v.x = fmaf(v.x, sc.x, sh.x);
        v.y = fmaf(v.y, sc.y, sh.y);
        v.z = fmaf(v.z, sc.z, sh.z);
        v.w = fmaf(v.w, sc.w, sh.w);
        ((float4*)h)[i] = v;
    }
}

// ---------------------------------------------------------------------------
extern "C" void kernel_launch(void* const* d_in, const int* in_sizes, int n_in,
                              void* d_out, int out_size, void* d_ws, size_t ws_size,
                              hipStream_t stream) {
    const float* x      = (const float*)d_in[0];
    const int*   ei     = (const int*)d_in[1];
    const float* W_l0   = (const float*)d_in[2];
    const float* b_l0   = (const float*)d_in[3];
    const float* W_r0   = (const float*)d_in[4];
    const float* gamma0 = (const float*)d_in[5];
    const float* beta0  = (const float*)d_in[6];
    const float* W_l1   = (const float*)d_in[7];
    const float* b_l1   = (const float*)d_in[8];
    const float* W_r1   = (const float*)d_in[9];
    const float* gamma1 = (const float*)d_in[10];
    const float* beta1  = (const float*)d_in[11];

    const int* src = ei;
    const int* dst = ei + N_EDGES;

    char* w = (char*)d_ws;
    auto alloc = [&](size_t bytes) {
        void* p = (void*)w;
        w += (bytes + 255) & ~(size_t)255;
        return p;
    };
    char* zbase    = w;
    float* gstats0 = (float*)alloc(sizeof(float) * NSLICE * 256);
    float* gstats1 = (float*)alloc(sizeof(float) * NSLICE * 256);
    int* bcursor   = (int*)alloc(sizeof(int) * BUCKS);
    size_t zbytes  = (size_t)(w - zbase);

    uint* ebuf     = (uint*)alloc(sizeof(uint) * (size_t)BUCKS * BSTRIDE);
    u16* sbuf      = (u16*)alloc(sizeof(u16) * (size_t)BUCKS * BSTRIDE);
    int* rob       = (int*)alloc(sizeof(int) * (size_t)BUCKS * 34);
    u16* xb        = (u16*)alloc(sizeof(u16) * (size_t)NPAD * 128);
    u16* hb        = (u16*)alloc(sizeof(u16) * (size_t)NPAD * 128);
    u16* aggb      = (u16*)alloc(sizeof(u16) * (size_t)NPAD * 128);
    u16* Wt        = (u16*)alloc(sizeof(u16) * 4 * 16384);
    float* outp    = (float*)d_out;

    hipMemsetAsync(zbase, 0, zbytes, stream);

    const float inv_n = 1.0f / (float)N_NODES;
    const int total4 = N_NODES * HID / 4;
    const int totalv = N_NODES * HID / 8;
    const int castN = NPAD * 128 + 4 * 16384;

    bucket_scatter_blk<<<(N_EDGES + 8191) / 8192, 1024, 0, stream>>>(src, dst, bcursor, ebuf);
    cast_all<<<(castN + 255) / 256, 256, 0, stream>>>(x, W_l0, W_r0, W_l1, W_r1, xb, Wt);
    bucket_sort<<<BUCKS, 64, 0, stream>>>(ebuf, bcursor, sbuf, rob);

    // Layer 0
    agg_sliced<<<BUCKS * 8, 64, 0, stream>>>(sbuf, rob, xb, aggb);
    gemm_all<1><<<BUCKS, 256, 0, stream>>>(aggb, xb, Wt, Wt + 16384, b_l0,
                                           nullptr, hb, gstats0);
    bn_relu_inplace<<<1024, 256, 0, stream>>>(hb, gstats0, gamma0, beta0, inv_n, totalv);

    // Layer 1
    agg_sliced<<<BUCKS * 8, 64, 0, stream>>>(sbuf, rob, hb, aggb);
    gemm_all<0><<<BUCKS, 256, 0, stream>>>(aggb, hb, Wt + 2 * 16384, Wt + 3 * 16384, b_l1,
                                           outp, nullptr, gstats1);
    bn_apply_kernel<<<2048, 256, 0, stream>>>(outp, gstats1, gamma1, beta1, inv_n, total4);
}

// Round 13
// 217.812 us; speedup vs baseline: 1.4603x; 1.4603x over previous
//
#include <hip/hip_runtime.h>
#include <hip/hip_bf16.h>

#define N_NODES 50000
#define N_EDGES 800000
#define BSHIFT  5
#define BUCKS   1563           // ceil(50000 / 32)
#define NPAD    50016          // BUCKS * 32
#define BSTRIDE 1024           // slots per bucket (mean 512, ~22 sigma headroom)
#define BCAP    1024
#define IN_DIM  100
#define HID     128
#define BN_EPS  1e-5f
#define NSLICE  32             // stats atomic slices (depth 1563/32 ~ 49 per address)

#define SC_BLKS 98             // scatter blocks: ceil(800000/8192)
#define CAST_ELEMS (NPAD * 128 + 4 * 16384)
#define CAST_BLKS ((CAST_ELEMS + 4095) / 4096)

typedef unsigned int uint;
typedef unsigned short u16;
typedef __attribute__((ext_vector_type(8))) unsigned short us8;
typedef __attribute__((ext_vector_type(8))) short s8;       // bf16 MFMA frag
typedef __attribute__((ext_vector_type(16))) float f16v;    // 32x32 accumulator

__device__ __forceinline__ u16 f2bf(float f) {
    uint u = __builtin_bit_cast(uint, f);
    uint r = (u + 0x7FFFu + ((u >> 16) & 1u)) >> 16;   // RNE
    return (u16)r;
}
__device__ __forceinline__ uint pack2(float a, float b) {
    return (uint)f2bf(a) | ((uint)f2bf(b) << 16);
}
__device__ __forceinline__ float bflo(uint p) { return __builtin_bit_cast(float, p << 16); }
__device__ __forceinline__ float bfhi(uint p) { return __builtin_bit_cast(float, p & 0xFFFF0000u); }
__device__ __forceinline__ float bfu(u16 v) { return __builtin_bit_cast(float, (uint)v << 16); }

// ---------------------------------------------------------------------------
// Fat preprocessing kernel: blocks [0,SC_BLKS) scatter edges into buckets;
// blocks [SC_BLKS, SC_BLKS+CAST_BLKS) cast x->bf16 padded + weights->bf16^T.
// ---------------------------------------------------------------------------
__global__ __launch_bounds__(1024) void scatter_cast(
    const int* __restrict__ src, const int* __restrict__ dst,
    int* __restrict__ bcursor, uint* __restrict__ ebuf,
    const float* __restrict__ x,
    const float* __restrict__ W_l0, const float* __restrict__ W_r0,
    const float* __restrict__ W_l1, const float* __restrict__ W_r1,
    u16* __restrict__ xb, u16* __restrict__ Wt) {
    __shared__ int h[BUCKS];
    __shared__ int gb[BUCKS];
    int t = threadIdx.x;

    if (blockIdx.x >= SC_BLKS) {
        // ---- cast phase
        int base = (blockIdx.x - SC_BLKS) * 4096 + t;
        #pragma unroll
        for (int r = 0; r < 4; ++r) {
            int idx = base + r * 1024;
            if (idx < NPAD * 128) {
                int row = idx >> 7, k = idx & 127;
                float v = (row < N_NODES && k < IN_DIM) ? x[row * IN_DIM + k] : 0.f;
                xb[idx] = f2bf(v);
            } else if (idx < CAST_ELEMS) {
                int i2 = idx - NPAD * 128;
                int w = i2 >> 14, i3 = i2 & 16383;
                const float* s = (w == 0) ? W_l0 : (w == 1) ? W_r0 : (w == 2) ? W_l1 : W_r1;
                int Ks = (w < 2) ? IN_DIM : HID;
                int n = i3 >> 7, k = i3 & 127;
                float v = (k < Ks) ? s[k * 128 + n] : 0.f;
                Wt[i2] = f2bf(v);
            }
        }
        return;
    }

    // ---- scatter phase
    for (int i = t; i < BUCKS; i += 1024) h[i] = 0;
    __syncthreads();
    int base = blockIdx.x * 8192;
    int myb[8]; uint myv[8];
    #pragma unroll
    for (int r = 0; r < 8; ++r) {
        int e = base + r * 1024 + t;
        int b = -1; uint val = 0;
        if (e < N_EDGES) {
            int d = dst[e];
            b = d >> BSHIFT;
            val = (uint)src[e] | ((uint)(d & 31) << 16);
            atomicAdd(&h[b], 1);
        }
        myb[r] = b; myv[r] = val;
    }
    __syncthreads();
    for (int i = t; i < BUCKS; i += 1024) {
        int c = h[i];
        gb[i] = c ? (i * BSTRIDE + atomicAdd(&bcursor[i], c)) : 0;
        h[i] = 0;
    }
    __syncthreads();
    #pragma unroll
    for (int r = 0; r < 8; ++r) {
        int b = myb[r];
        if (b >= 0) {
            int pos = gb[b] + atomicAdd(&h[b], 1);
            ebuf[pos] = myv[r];
        }
    }
}

// ---------------------------------------------------------------------------
// Fused per-bucket kernel (round-11 v6 + optional on-the-fly BN+ReLU of X):
// 32-node buckets, 256-thread blocks. LDS CSR -> quad-owns-node gather-mean
// (BN applied per element if APPLY_BN) -> 32x32x16 MFMA (B/root-A direct
// from global; root-A BN-transformed in regs) -> store + fp32 BN stats.
// ---------------------------------------------------------------------------
template <int APPLY_BN, int WRITE_BF16>
__global__ __launch_bounds__(256) void agg_gemm(
    const uint* __restrict__ ebuf, const int* __restrict__ bcursor,
    const u16* __restrict__ X,
    const u16* __restrict__ WtL, const u16* __restrict__ WtR,
    const float* __restrict__ bias,
    float* __restrict__ outf, u16* __restrict__ outb,
    float* __restrict__ gstats_out,
    const float* __restrict__ gstats_in,
    const float* __restrict__ gamma, const float* __restrict__ beta,
    float inv_n) {
    __shared__ u16 Aagg[32][136];        // 8704 B
    __shared__ uint eL[BCAP];            // 4096 B
    __shared__ u16 srcL[BCAP];           // 2048 B
    __shared__ int cnt[32], ro[33], cur[32];
    __shared__ float s1L[128], s2L[128];
    __shared__ float ss[256];            // BN scale/shift (APPLY_BN)

    int b = blockIdx.x;
    int t = threadIdx.x;
    int row0 = b * 32;
    int wave = t >> 6, lane = t & 63;
    int quad = lane >> 4, sub = lane & 15;

    // ---- preamble: BN scale/shift from layer-0 stats (L2-hot, 32 KB)
    if (APPLY_BN && t < 128) {
        float m = 0.f, q = 0.f;
        #pragma unroll
        for (int s = 0; s < NSLICE; ++s) {
            m += gstats_in[s * 256 + t];
            q += gstats_in[s * 256 + 128 + t];
        }
        float mean = m * inv_n;
        float var = q * inv_n - mean * mean;
        float inv = 1.0f / sqrtf(var + BN_EPS);
        float sc = gamma[t] * inv;
        ss[t] = sc;
        ss[128 + t] = beta[t] - mean * sc;
    }

    // ---- bucket-local CSR in LDS
    int n = bcursor[b];
    if (n > BCAP) n = BCAP;
    if (t < 32) cnt[t] = 0;
    if (t < 128) { s1L[t] = 0.f; s2L[t] = 0.f; }
    __syncthreads();
    for (int i = t; i < n; i += 256) {
        uint p = ebuf[b * BSTRIDE + i];
        eL[i] = p;
        atomicAdd(&cnt[p >> 16], 1);
    }
    __syncthreads();
    if (t < 32) {
        int v = cnt[t];
        int s = v;
        #pragma unroll
        for (int off = 1; off < 32; off <<= 1) {
            int u = __shfl_up(s, off, 64);
            if (t >= off) s += u;
        }
        ro[t] = s - v;
        cur[t] = s - v;
        if (t == 31) ro[32] = s;
    }
    __syncthreads();
    for (int i = t; i < n; i += 256) {
        uint p = eL[i];
        int pos = atomicAdd(&cur[p >> 16], 1);
        srcL[pos] = (u16)(p & 0xFFFFu);
    }
    __syncthreads();

    // ---- gather-mean: each of 16 quads owns 2 nodes
    float scr[8], shr[8];
    if (APPLY_BN) {
        #pragma unroll
        for (int j = 0; j < 8; ++j) {
            scr[j] = ss[sub * 8 + j];
            shr[j] = ss[128 + sub * 8 + j];
        }
    }
    int nl0 = (wave * 4 + quad) * 2;
    #pragma unroll
    for (int g = 0; g < 2; ++g) {
        int nl = nl0 + g;
        int rb = ro[nl], re = ro[nl + 1];
        float a[8];
        #pragma unroll
        for (int j = 0; j < 8; ++j) a[j] = 0.f;

        auto acc1 = [&](uint4 v) {
            float f[8] = { bflo(v.x), bfhi(v.x), bflo(v.y), bfhi(v.y),
                           bflo(v.z), bfhi(v.z), bflo(v.w), bfhi(v.w) };
            #pragma unroll
            for (int j = 0; j < 8; ++j) {
                float val = f[j];
                if (APPLY_BN) val = fmaxf(fmaf(val, scr[j], shr[j]), 0.f);
                a[j] += val;
            }
        };

        int e = rb;
        for (; e + 4 <= re; e += 4) {
            int s0 = srcL[e], s1 = srcL[e + 1], s2 = srcL[e + 2], s3 = srcL[e + 3];
            uint4 v0 = ((const uint4*)(X + (size_t)s0 * 128))[sub];
            uint4 v1 = ((const uint4*)(X + (size_t)s1 * 128))[sub];
            uint4 v2 = ((const uint4*)(X + (size_t)s2 * 128))[sub];
            uint4 v3 = ((const uint4*)(X + (size_t)s3 * 128))[sub];
            acc1(v0); acc1(v1); acc1(v2); acc1(v3);
        }
        for (; e < re; ++e) {
            uint4 v0 = ((const uint4*)(X + (size_t)srcL[e] * 128))[sub];
            acc1(v0);
        }
        float inv = 1.0f / fmaxf((float)(re - rb), 1.0f);
        uint4 o;
        o.x = pack2(a[0] * inv, a[1] * inv);
        o.y = pack2(a[2] * inv, a[3] * inv);
        o.z = pack2(a[4] * inv, a[5] * inv);
        o.w = pack2(a[6] * inv, a[7] * inv);
        *(uint4*)&Aagg[nl][sub * 8] = o;
    }
    __syncthreads();   // Aagg complete

    // ---- dual GEMM: wave -> rows 0..31 of tile, cols cn..cn+31
    int m31 = lane & 31;
    int kh  = lane >> 5;
    int cn = wave * 32;
    f16v acc = (f16v)0.f;

    {
        s8 a_nxt = *(const s8*)&Aagg[m31][kh * 8];
        s8 b_nxt = *(const s8*)(WtL + (cn + m31) * 128 + kh * 8);
        #pragma unroll
        for (int ks = 0; ks < 8; ++ks) {
            s8 a_cur = a_nxt, b_cur = b_nxt;
            if (ks < 7) {
                a_nxt = *(const s8*)&Aagg[m31][(ks + 1) * 16 + kh * 8];
                b_nxt = *(const s8*)(WtL + (cn + m31) * 128 + (ks + 1) * 16 + kh * 8);
            }
            acc = __builtin_amdgcn_mfma_f32_32x32x16_bf16(a_cur, b_cur, acc, 0, 0, 0);
        }
    }
    {
        const u16* xrow = X + (size_t)(row0 + m31) * 128;
        us8 a_nxt = *(const us8*)(xrow + kh * 8);
        s8 b_nxt = *(const s8*)(WtR + (cn + m31) * 128 + kh * 8);
        #pragma unroll
        for (int ks = 0; ks < 8; ++ks) {
            us8 a_raw = a_nxt;
            s8 b_cur = b_nxt;
            if (ks < 7) {
                a_nxt = *(const us8*)(xrow + (ks + 1) * 16 + kh * 8);
                b_nxt = *(const s8*)(WtR + (cn + m31) * 128 + (ks + 1) * 16 + kh * 8);
            }
            s8 a_cur;
            if (APPLY_BN) {
                int kb = ks * 16 + kh * 8;
                #pragma unroll
                for (int j = 0; j < 8; ++j) {
                    float f = bfu(a_raw[j]);
                    f = fmaxf(fmaf(f, ss[kb + j], ss[128 + kb + j]), 0.f);
                    a_cur[j] = (short)f2bf(f);
                }
            } else {
                a_cur = __builtin_bit_cast(s8, a_raw);
            }
            acc = __builtin_amdgcn_mfma_f32_32x32x16_bf16(a_cur, b_cur, acc, 0, 0, 0);
        }
    }

    // ---- epilogue: store + BN partial stats
    // C/D 32x32: col=lane&31, row=(reg&3)+8*(reg>>2)+4*(lane>>5)  [m74/m101]
    {
        int col = cn + m31;
        float bv = bias[col];
        float s1 = 0.f, s2 = 0.f;
        #pragma unroll
        for (int reg = 0; reg < 16; ++reg) {
            int rowin = (reg & 3) + 8 * (reg >> 2) + 4 * kh;
            int row = row0 + rowin;
            if (row < N_NODES) {
                float v = acc[reg] + bv;
                if (WRITE_BF16)
                    outb[(size_t)row * 128 + col] = f2bf(v);
                else
                    outf[(size_t)row * 128 + col] = v;
                s1 += v;
                s2 = fmaf(v, v, s2);
            }
        }
        s1 += __shfl_xor(s1, 32, 64);
        s2 += __shfl_xor(s2, 32, 64);
        if (lane < 32) {
            atomicAdd(&s1L[col], s1);
            atomicAdd(&s2L[col], s2);
        }
    }
    __syncthreads();
    int slice = b & (NSLICE - 1);
    if (t < 128) {
        atomicAdd(&gstats_out[slice * 256 + t], s1L[t]);
        atomicAdd(&gstats_out[slice * 256 + 128 + t], s2L[t]);
    }
}

// ---------------------------------------------------------------------------
// final BN, fp32 in-place on d_out
// ---------------------------------------------------------------------------
__global__ void bn_apply_kernel(float* __restrict__ h,
                                const float* __restrict__ gstats,
                                const float* __restrict__ gamma,
                                const float* __restrict__ beta,
                                float inv_n, int total4) {
    __shared__ float ss[256];
    int t = threadIdx.x;
    if (t < 128) {
        float m = 0.f, q = 0.f;
        #pragma unroll
        for (int s = 0; s < NSLICE; ++s) {
            m += gstats[s * 256 + t];
            q += gstats[s * 256 + 128 + t];
        }
        float mean = m * inv_n;
        float var = q * inv_n - mean * mean;
        float inv = 1.0f / sqrtf(var + BN_EPS);
        float sc = gamma[t] * inv;
        ss[t] = sc;
        ss[128 + t] = beta[t] - mean * sc;
    }
    __syncthreads();
    for (int i = blockIdx.x * 256 + t; i < total4; i += gridDim.x * 256) {
        int cg = i & 31;
        float4 v = ((float4*)h)[i];
        float4 sc = *(const float4*)&ss[cg * 4];
        float4 sh = *(const float4*)&ss[128 + cg * 4];
        v.x = fmaf(v.x, sc.x, sh.x);
        v.y = fmaf(v.y, sc.y, sh.y);
        v.z = fmaf(v.z, sc.z, sh.z);
        v.w = fmaf(v.w, sc.w, sh.w);
        ((float4*)h)[i] = v;
    }
}

// ---------------------------------------------------------------------------
extern "C" void kernel_launch(void* const* d_in, const int* in_sizes, int n_in,
                              void* d_out, int out_size, void* d_ws, size_t ws_size,
                              hipStream_t stream) {
    const float* x      = (const float*)d_in[0];
    const int*   ei     = (const int*)d_in[1];
    const float* W_l0   = (const float*)d_in[2];
    const float* b_l0   = (const float*)d_in[3];
    const float* W_r0   = (const float*)d_in[4];
    const float* gamma0 = (const float*)d_in[5];
    const float* beta0  = (const float*)d_in[6];
    const float* W_l1   = (const float*)d_in[7];
    const float* b_l1   = (const float*)d_in[8];
    const float* W_r1   = (const float*)d_in[9];
    const float* gamma1 = (const float*)d_in[10];
    const float* beta1  = (const float*)d_in[11];

    const int* src = ei;
    const int* dst = ei + N_EDGES;

    char* w = (char*)d_ws;
    auto alloc = [&](size_t bytes) {
        void* p = (void*)w;
        w += (bytes + 255) & ~(size_t)255;
        return p;
    };
    char* zbase    = w;
    float* gstats0 = (float*)alloc(sizeof(float) * NSLICE * 256);
    float* gstats1 = (float*)alloc(sizeof(float) * NSLICE * 256);
    int* bcursor   = (int*)alloc(sizeof(int) * BUCKS);
    size_t zbytes  = (size_t)(w - zbase);

    uint* ebuf     = (uint*)alloc(sizeof(uint) * (size_t)BUCKS * BSTRIDE);
    u16* xb        = (u16*)alloc(sizeof(u16) * (size_t)NPAD * 128);
    u16* hb        = (u16*)alloc(sizeof(u16) * (size_t)NPAD * 128);
    u16* Wt        = (u16*)alloc(sizeof(u16) * 4 * 16384);
    float* outp    = (float*)d_out;

    hipMemsetAsync(zbase, 0, zbytes, stream);

    const float inv_n = 1.0f / (float)N_NODES;
    const int total4 = N_NODES * HID / 4;

    // preprocessing: scatter + casts, one launch
    scatter_cast<<<SC_BLKS + CAST_BLKS, 1024, 0, stream>>>(
        src, dst, bcursor, ebuf, x, W_l0, W_r0, W_l1, W_r1, xb, Wt);

    // Layer 0: fused agg+gemm+stats, h -> raw bf16 hb
    agg_gemm<0, 1><<<BUCKS, 256, 0, stream>>>(
        ebuf, bcursor, xb, Wt, Wt + 16384, b_l0,
        nullptr, hb, gstats0, nullptr, nullptr, nullptr, inv_n);

    // Layer 1: fused agg+gemm+stats with on-the-fly BN+ReLU of h -> fp32 d_out
    agg_gemm<1, 0><<<BUCKS, 256, 0, stream>>>(
        ebuf, bcursor, hb, Wt + 2 * 16384, Wt + 3 * 16384, b_l1,
        outp, nullptr, gstats1, gstats0, gamma0, beta0, inv_n);

    bn_apply_kernel<<<2048, 256, 0, stream>>>(outp, gstats1, gamma1, beta1, inv_n, total4);
}